// Round 3
// baseline (174.905 us; speedup 1.0000x reference)
//
#include <hip/hip_runtime.h>

// ---------------------------------------------------------------------------
// FixedRateVectorQuantizer (N=131072, D=128, P=512), Mahalanobis VQ.
// Out: [N*D quantized][commit][cb_loss][N idx-as-float]  (fp32)
//
// Whitened: S = inv(cov) ~ L L^T, L = sqrt(c)[(3/2)I - (c/2)cov], c = 128/tr
//   y = x L, chat_p = c_p L  ->  d(x,c_p) = |y - chat_p|^2
//   argmin_p d = argmax_p packed(y.chat_p + 1024 - |chat|^2/2, tag=511-idx)
//   min_p d = |y|^2 - 2*(max_val - 1024);  M = mean_r min d;  commit = 0.1 M
//   cb_loss = M - 2e5 * entropy(counts)
// 4 dispatches: k_prep1 (64), k_prep2 (32), k_main (1024), k_final (1).
//
// R3 (deep pipeline + register relief):
//   - unified 40-tile B-sweep (8 Lh + 32 Ch), quad-buffered LDS staging,
//     counted s_waitcnt vmcnt(2) + raw s_barrier (loads stay in flight
//     across barriers; never drain vmcnt(0) in the loop).
//   - cq table in LDS (2KB) so the only in-loop vmem ops are the stage
//     loads -> vmcnt arithmetic is exact.
//   - __launch_bounds__(256,3): LDS already limits to 3 blocks/CU, so the
//     old ",4" register cap only forced spills (VGPR_Count 64, WRITE +25MB).
//   - LDS = 32768 (Xs) + 16384 (Bst x4) + 2048 (cq) = 51200 B.
// ---------------------------------------------------------------------------

typedef _Float16 half8 __attribute__((ext_vector_type(8)));
typedef float floatx4 __attribute__((ext_vector_type(4)));

#define NROWS 131072
#define DIM 128
#define NCODE 512
#define ND 16777216

// ---- workspace layout (bytes) ----
#define WS_LH    0        // 128x128 f16 (L, symmetric), XOR-swizzled rows
#define WS_CH    32768    // 512x128 f16 (C*L), XOR-swizzled rows
#define WS_CQ    163840   // 512 f32  (1024 - 0.5|chat|^2)
#define WS_CNT   165888   // 8 x 512 u32 (XCD replicas, zeroed by k_prep1)
#define WS_SUMS  182272   // 8 x 32 f32  (XCD replicas, zeroed by k_prep1)

#define MFMA16(A, B, C) __builtin_amdgcn_mfma_f32_16x16x32_f16(A, B, C, 0, 0, 0)

// byte offset of element (row, colh[halfwords]) in a 256B-row f16 matrix,
// with XOR swizzle spreading the 16 rows of a tile across banks.
__device__ __forceinline__ int moff(int row, int colh) {
  return row * 256 + ((((row & 7) << 4) ^ (colh * 2)));
}

// stage one 4KB tile (16 rows x 256B) from global to LDS, linear copy.
// 256 threads x 16B. LDS dest is wave-uniform base; HW adds lane*16.
__device__ __forceinline__ void stage4k(const char* src, char* ldsbase,
                                        int w, int lane) {
  __builtin_amdgcn_global_load_lds(
      (const __attribute__((address_space(1))) void*)(src + (w * 1024 + lane * 16)),
      (__attribute__((address_space(3))) void*)(ldsbase + w * 1024),
      16, 0, 0);
}

// ---------------- prep1: mu, trace, L rows (f16); zero counters ----------
// 64 blocks x 256. Block b: L rows 2b, 2b+1 (Gram trick, no cov materialized).
__global__ __launch_bounds__(256) void k_prep1(
    const float* __restrict__ cb, _Float16* __restrict__ Lh,
    unsigned* __restrict__ cnt, float* __restrict__ sums) {
  __shared__ float mu[128];
  __shared__ float red[256];
  __shared__ float colI[2][512];
  __shared__ float csh[2];

  const int t = threadIdx.x, b = blockIdx.x;
  const int j = t & 127, h = t >> 7;

  // zero atomic replicas for k_main
  if (b < 8) {
    cnt[b * 512 + t] = 0u;
    cnt[b * 512 + 256 + t] = 0u;
  }
  if (b == 8) sums[t] = 0.f;  // only t<256 exists; sums is 256 floats

  // column means + column sumsq (for trace)
  float sm = 0.f, sf = 0.f;
  for (int p = 0; p < 256; ++p) {
    float v = cb[(h * 256 + p) * DIM + j];
    sm += v;
    sf += v * v;
  }
  red[t] = sm;
  // stage columns 2b, 2b+1
  for (int k = t; k < 1024; k += 256)
    colI[k >> 9][k & 511] = cb[(k & 511) * DIM + 2 * b + (k >> 9)];
  __syncthreads();
  if (t < 128) mu[t] = (red[t] + red[t + 128]) * (1.f / 512.f);
  __syncthreads();
  red[t] = sf - ((t < 128) ? 512.f * mu[t] * mu[t] : 0.f);
  __syncthreads();
  for (int k = 128; k > 0; k >>= 1) {
    if (t < k) red[t] += red[t + k];
    __syncthreads();
  }
  if (t == 0) {
    float tr = red[0] * (1.f / 511.f) + 0.128f;  // + 128*1e-3 ridge
    csh[0] = 128.f / tr;
    csh[1] = sqrtf(128.f / tr);
  }
  __syncthreads();
  const float c = csh[0], rc = csh[1];

  // L row i = 2b+h:  L = rc*[ (1.5 - 5e-4c) I - (c/1022)(G - 512 mu mu^T) ]
  const int i = 2 * b + h;
  float g = 0.f;
  for (int q = 0; q < 512; ++q) g += colI[h][q] * cb[q * DIM + j];
  float lv = rc * (((i == j) ? (1.5f - 5e-4f * c) : 0.f) -
                   (c / 1022.f) * (g - 512.f * mu[i] * mu[j]));
  *(_Float16*)((char*)Lh + moff(i, j)) = (_Float16)lv;  // swizzled store
}

// ---------------- prep2: Chat = C*L (f16 MFMA, L symmetric), cqb ----------
// 32 blocks x 256. Block b: codes p0=16b..p0+15.
__global__ __launch_bounds__(256) void k_prep2(
    const float* __restrict__ cb, const _Float16* __restrict__ Lh,
    _Float16* __restrict__ Ch, float* __restrict__ cqb) {
  __shared__ float cqpart[16][4];
  const int t = threadIdx.x;
  const int w = t >> 6, lane = t & 63, quad = lane >> 4, l16 = lane & 15;
  const int p0 = blockIdx.x * 16;

  // A fragment: A[m=l16][k=quad*8+jj] = cb[p0+l16][k] (fp32 -> f16)
  half8 a[4];
#pragma unroll
  for (int ci = 0; ci < 4; ++ci) {
    const float4* v = (const float4*)(cb + (p0 + l16) * DIM + ci * 32 + quad * 8);
    float4 v0 = v[0], v1 = v[1];
    half8 hh;
    hh[0] = (_Float16)v0.x; hh[1] = (_Float16)v0.y;
    hh[2] = (_Float16)v0.z; hh[3] = (_Float16)v0.w;
    hh[4] = (_Float16)v1.x; hh[5] = (_Float16)v1.y;
    hh[6] = (_Float16)v1.z; hh[7] = (_Float16)v1.w;
    a[ci] = hh;
  }
  float sq[4] = {0.f, 0.f, 0.f, 0.f};
#pragma unroll
  for (int t2 = 0; t2 < 2; ++t2) {
    const int tile = w * 2 + t2;  // col tile: cols tile*16..+15
    floatx4 s = {0.f, 0.f, 0.f, 0.f};
#pragma unroll
    for (int ci = 0; ci < 4; ++ci) {
      // B[n][k] = L[k][n] = Lh[n][k] by symmetry -> swizzled row read
      half8 bb = *(const half8*)((const char*)Lh +
                                 moff(tile * 16 + l16, ci * 32 + quad * 8));
      s = MFMA16(a[ci], bb, s);
    }
#pragma unroll
    for (int r = 0; r < 4; ++r) {
      *(_Float16*)((char*)Ch + moff(p0 + quad * 4 + r, tile * 16 + l16)) =
          (_Float16)s[r];  // swizzled store
      sq[r] += s[r] * s[r];
    }
  }
#pragma unroll
  for (int r = 0; r < 4; ++r) {
    float v = sq[r];
    v += __shfl_xor(v, 1); v += __shfl_xor(v, 2);
    v += __shfl_xor(v, 4); v += __shfl_xor(v, 8);
    sq[r] = v;
  }
  if (l16 == 0)
#pragma unroll
    for (int r = 0; r < 4; ++r) cqpart[quad * 4 + r][w] = sq[r];
  __syncthreads();
  if (t < 16)
    cqb[p0 + t] = 1024.f - 0.5f * (cqpart[t][0] + cqpart[t][1] +
                                   cqpart[t][2] + cqpart[t][3]);
}

// ---------------- main fused kernel ----------------
// 1024 blocks x 256 (128 rows/block; wave owns 32 rows; 3 blocks/CU).
// Unified 40-tile B sweep (8 Lh + 32 Ch), quad-buffered LDS staging with
// counted vmcnt + raw barriers (loads in flight across barriers).
__global__ __launch_bounds__(256, 3) void k_main(
    const float* __restrict__ X, const float* __restrict__ cb,
    const _Float16* __restrict__ Lh, const _Float16* __restrict__ Ch,
    const float* __restrict__ cqb, float* __restrict__ out,
    unsigned* __restrict__ cnt, float* __restrict__ sums) {
  __shared__ __align__(16) char Xs[32768];      // 128x128 f16, XOR-swizzled
  __shared__ __align__(16) char Bst[4][4096];   // B-tile quad buffer
  __shared__ float cqs[512];

  const int tid = threadIdx.x;
  const int w = tid >> 6, lane = tid & 63;
  const int quad = lane >> 4, l16 = lane & 15;
  const int R0 = blockIdx.x * 128;
  const int rep = blockIdx.x & 7;
  const int r0 = w * 32;                         // this wave's 32 rows
  const int brot = (blockIdx.x >> 3) & 31;       // Ch sweep rotation (block)

  const char* LhB = (const char*)Lh;
  const char* ChB = (const char*)Ch;

  // ---- Phase A: stage 128x128 fp32 -> f16 LDS (block-wide, swizzled) ----
  {
    const float4* src = (const float4*)(X + (size_t)R0 * DIM);
#pragma unroll
    for (int it = 0; it < 8; ++it) {
      int g = it * 256 + tid;  // 32B f32 granule id (2048 total)
      int row = g >> 4, c8 = g & 15;
      float4 v0 = src[g * 2];
      float4 v1 = src[g * 2 + 1];
      half8 hh;
      hh[0] = (_Float16)v0.x; hh[1] = (_Float16)v0.y;
      hh[2] = (_Float16)v0.z; hh[3] = (_Float16)v0.w;
      hh[4] = (_Float16)v1.x; hh[5] = (_Float16)v1.y;
      hh[6] = (_Float16)v1.z; hh[7] = (_Float16)v1.w;
      *(half8*)(Xs + moff(row, c8 * 8)) = hh;
    }
    cqs[tid] = cqb[tid];
    cqs[256 + tid] = cqb[256 + tid];
  }

  // prologue: prefetch B tiles 0..2 (Lh tiles 0..2) into quad buffer
  stage4k(LhB, Bst[0], w, lane);
  stage4k(LhB + 4096, Bst[1], w, lane);
  stage4k(LhB + 8192, Bst[2], w, lane);
  __syncthreads();  // drains everything once; pipeline starts clean

  // A fragments (X rows of this wave)
  half8 a0[4], a1[4];
#pragma unroll
  for (int ci = 0; ci < 4; ++ci) {
    a0[ci] = *(const half8*)(Xs + moff(r0 + l16, ci * 32 + quad * 8));
    a1[ci] = *(const half8*)(Xs + moff(r0 + 16 + l16, ci * 32 + quad * 8));
  }

  // ---- Loop B: tiles 0..7 (Y = X @ L, in place) ----
  // invariant at iter v: issued stages 0..v+2; wait vmcnt(2) => stage(v) done
  float y2 = 0.f;
  for (int v = 0; v < 8; ++v) {
    asm volatile("s_waitcnt vmcnt(2)" ::: "memory");  // own stage(v) landed
    __builtin_amdgcn_s_barrier();  // all waves: stage(v) landed; buf v-1 free
    asm volatile("" ::: "memory");
    // stage tile v+3 (Lh, or first Ch tiles) into buffer (v+3)&3
    const int t3 = v + 3;
    const char* nsrc = (t3 < 8) ? (LhB + (size_t)t3 * 4096)
                                : (ChB + (size_t)((t3 - 8 + brot) & 31) * 4096);
    stage4k(nsrc, Bst[t3 & 3], w, lane);

    const char* lb = Bst[v & 3];
    half8 bb[4];
#pragma unroll
    for (int ci = 0; ci < 4; ++ci)
      bb[ci] = *(const half8*)(lb + moff(l16, ci * 32 + quad * 8));
    floatx4 s0 = {0.f, 0.f, 0.f, 0.f}, s1 = {0.f, 0.f, 0.f, 0.f};
    __builtin_amdgcn_s_setprio(1);
#pragma unroll
    for (int ci = 0; ci < 4; ++ci) {
      s0 = MFMA16(a0[ci], bb[ci], s0);
      s1 = MFMA16(a1[ci], bb[ci], s1);
    }
    __builtin_amdgcn_s_setprio(0);
    const int col = v * 16 + l16;
#pragma unroll
    for (int r = 0; r < 4; ++r) {
      y2 += s0[r] * s0[r] + s1[r] * s1[r];
      *(_Float16*)(Xs + moff(r0 + quad * 4 + r, col)) = (_Float16)s0[r];
      *(_Float16*)(Xs + moff(r0 + 16 + quad * 4 + r, col)) = (_Float16)s1[r];
    }
  }

  // reload A fragments with Y values (own rows; same-wave write->read order)
#pragma unroll
  for (int ci = 0; ci < 4; ++ci) {
    a0[ci] = *(const half8*)(Xs + moff(r0 + l16, ci * 32 + quad * 8));
    a1[ci] = *(const half8*)(Xs + moff(r0 + 16 + l16, ci * 32 + quad * 8));
  }

  // ---- Loop C: tiles 8..39 (packed argmax over 32 Ch tiles) ----
  float m0[4] = {0.f, 0.f, 0.f, 0.f}, m1[4] = {0.f, 0.f, 0.f, 0.f};
  for (int v = 8; v < 40; ++v) {
    asm volatile("s_waitcnt vmcnt(2)" ::: "memory");
    __builtin_amdgcn_s_barrier();
    asm volatile("" ::: "memory");
    // always stage (wraps past the end: harmless redundant 4KB reload,
    // keeps the vmcnt invariant uniform; target buffer already consumed)
    stage4k(ChB + (size_t)((v - 5 + brot) & 31) * 4096, Bst[(v + 3) & 3], w, lane);

    const int tt = (v - 8 + brot) & 31;
    const float iv = cqs[tt * 16 + l16];
    const char* lb = Bst[v & 3];
    half8 bb[4];
#pragma unroll
    for (int ci = 0; ci < 4; ++ci)
      bb[ci] = *(const half8*)(lb + moff(l16, ci * 32 + quad * 8));
    floatx4 s0a = {iv, iv, iv, iv}, s0b = {0.f, 0.f, 0.f, 0.f};
    floatx4 s1a = {iv, iv, iv, iv}, s1b = {0.f, 0.f, 0.f, 0.f};
    __builtin_amdgcn_s_setprio(1);
    s0a = MFMA16(a0[0], bb[0], s0a); s0b = MFMA16(a0[1], bb[1], s0b);
    s1a = MFMA16(a1[0], bb[0], s1a); s1b = MFMA16(a1[1], bb[1], s1b);
    s0a = MFMA16(a0[2], bb[2], s0a); s0b = MFMA16(a0[3], bb[3], s0b);
    s1a = MFMA16(a1[2], bb[2], s1a); s1b = MFMA16(a1[3], bb[3], s1b);
    __builtin_amdgcn_s_setprio(0);
    const unsigned tag = 511u - (unsigned)(tt * 16 + l16);
#pragma unroll
    for (int r = 0; r < 4; ++r) {
      float v0 = s0a[r] + s0b[r], v1 = s1a[r] + s1b[r];
      unsigned u0 = ((__float_as_uint(v0) + 0x100u) & 0xFFFFFE00u) | tag;
      unsigned u1 = ((__float_as_uint(v1) + 0x100u) & 0xFFFFFE00u) | tag;
      m0[r] = fmaxf(m0[r], __uint_as_float(u0));
      m1[r] = fmaxf(m1[r], __uint_as_float(u1));
    }
  }

  // cross-lane max over the 16 lanes sharing each row (packed: ties -> low idx)
#pragma unroll
  for (int r = 0; r < 4; ++r) {
#pragma unroll
    for (int msk = 1; msk < 16; msk <<= 1) {
      m0[r] = fmaxf(m0[r], __shfl_xor(m0[r], msk));
      m1[r] = fmaxf(m1[r], __shfl_xor(m1[r], msk));
    }
  }

  // ---- epilogue (no LDS needed: every lane of quad q knows its 8 rows) ----
  float contrib = y2;
  if (l16 == 0) {
#pragma unroll
    for (int r = 0; r < 4; ++r) {
      contrib -= 2.f * (__uint_as_float(__float_as_uint(m0[r]) & 0xFFFFFE00u) - 1024.f);
      contrib -= 2.f * (__uint_as_float(__float_as_uint(m1[r]) & 0xFFFFFE00u) - 1024.f);
    }
  }
#pragma unroll
  for (int msk = 1; msk < 64; msk <<= 1) contrib += __shfl_xor(contrib, msk);
  if (lane == 0) unsafeAtomicAdd(&sums[rep * 32], contrib);

  // gather quantized rows (codebook L2-resident) + idx store + histogram
  {
    const float4* cb4 = (const float4*)cb;
    float4* out4 = (float4*)out;
#pragma unroll
    for (int r = 0; r < 4; ++r) {
      const int j0 = 511 - (int)(__float_as_uint(m0[r]) & 511u);
      const int j1 = 511 - (int)(__float_as_uint(m1[r]) & 511u);
      const int row0 = R0 + r0 + quad * 4 + r, row1 = row0 + 16;
      out4[(size_t)row0 * 32 + l16 * 2]     = cb4[(size_t)j0 * 32 + l16 * 2];
      out4[(size_t)row0 * 32 + l16 * 2 + 1] = cb4[(size_t)j0 * 32 + l16 * 2 + 1];
      out4[(size_t)row1 * 32 + l16 * 2]     = cb4[(size_t)j1 * 32 + l16 * 2];
      out4[(size_t)row1 * 32 + l16 * 2 + 1] = cb4[(size_t)j1 * 32 + l16 * 2 + 1];
      if (l16 == 0) {
        out[ND + 2 + row0] = (float)j0;
        out[ND + 2 + row1] = (float)j1;
        atomicAdd(&cnt[rep * 512 + j0], 1u);
        atomicAdd(&cnt[rep * 512 + j1], 1u);
      }
    }
  }
}

// ---------------- finalize: entropy + losses ----------------
__global__ void k_final(const unsigned* __restrict__ cnt,
                        const float* __restrict__ sums, float* __restrict__ out) {
  __shared__ double sd[256];
  int t = threadIdx.x;
  double e = 0.0;
  for (int c = t; c < NCODE; c += 256) {
    unsigned u = 0;
#pragma unroll
    for (int r = 0; r < 8; ++r) u += cnt[r * 512 + c];
    float p = (float)u * (1.0f / 131072.0f);
    e += (double)(p * logf(p + 1e-8f));
  }
  sd[t] = e;
  __syncthreads();
  for (int k = 128; k > 0; k >>= 1) {
    if (t < k) sd[t] += sd[t + k];
    __syncthreads();
  }
  if (t == 0) {
    double ent = -sd[0];
    float st = 0.f;
#pragma unroll
    for (int r = 0; r < 8; ++r) st += sums[r * 32];
    double M = (double)st / 131072.0;
    out[ND] = (float)(0.1 * M);
    out[ND + 1] = (float)(M - 200000.0 * ent);
  }
}

// ---------------- launcher ----------------
extern "C" void kernel_launch(void* const* d_in, const int* in_sizes, int n_in,
                              void* d_out, int out_size, void* d_ws, size_t ws_size,
                              hipStream_t stream) {
  const float* X = (const float*)d_in[0];
  const float* cb = (const float*)d_in[1];
  char* ws = (char*)d_ws;
  _Float16* Lh = (_Float16*)(ws + WS_LH);
  _Float16* Ch = (_Float16*)(ws + WS_CH);
  float* cqb = (float*)(ws + WS_CQ);
  unsigned* cnt = (unsigned*)(ws + WS_CNT);
  float* sums = (float*)(ws + WS_SUMS);
  float* out = (float*)d_out;

  k_prep1<<<64, 256, 0, stream>>>(cb, Lh, cnt, sums);
  k_prep2<<<32, 256, 0, stream>>>(cb, Lh, Ch, cqb);
  k_main<<<1024, 256, 0, stream>>>(X, cb, Lh, Ch, cqb, out, cnt, sums);
  k_final<<<1, 256, 0, stream>>>(cnt, sums, out);
}

// Round 4
// 166.789 us; speedup vs baseline: 1.0487x; 1.0487x over previous
//
#include <hip/hip_runtime.h>

// ---------------------------------------------------------------------------
// FixedRateVectorQuantizer (N=131072, D=128, P=512), Mahalanobis VQ.
// Out: [N*D quantized][commit][cb_loss][N idx-as-float]  (fp32)
//
// Whitened: S = inv(cov) ~ L L^T, L = sqrt(c)[(3/2)I - (c/2)cov], c = 128/tr
//   scores_p = x.(S c_p) = x.w_p with W = C S = Ch L  (Ch = C L, L symm)
//   argmin_p d = argmax_p packed(x.w_p + 1024 - |chat_p|^2/2, tag=511-idx)
//   xSx = sum((X Sh) .* X), Sh = L L
//   min_p d = xSx - 2*(max_val - 1024);  M = mean_r min d;  commit = 0.1 M
//   cb_loss = M - 2e5 * entropy(counts)
// 5 dispatches: k_prep1 (64), k_prep2 (32), k_prep3 (40), k_main (1024),
//   k_final (1).
//
// R4 (occupancy + single-pass):
//   - LDS = 32768 (Xs) + 2x4096 (Bst) = 40960 B = exactly 160KiB/4
//     -> 4 blocks/CU (R2's proven best regime), launch_bounds(256,3) so the
//     allocator is NOT reg-capped (R2's ",4" forced 64 VGPR + 19MB spills).
//   - W-transform: scores computed directly from staged X (one A-frag load,
//     no in-place Y writes -> kills the 2.88M LDS bank conflicts, no phase
//     boundary). y2 via 8 Sh tiles + z.x dot (scalar LDS reads, conflict-free).
//   - cq read per-iter from global (64B L1-hot line), no cqs LDS.
// ---------------------------------------------------------------------------

typedef _Float16 half8 __attribute__((ext_vector_type(8)));
typedef float floatx4 __attribute__((ext_vector_type(4)));

#define NROWS 131072
#define DIM 128
#define NCODE 512
#define ND 16777216

// ---- workspace layout (bytes) ----
#define WS_LH    0        // 128x128 f16 (L, symmetric), XOR-swizzled rows
#define WS_CH    32768    // 512x128 f16 (C*L), XOR-swizzled rows
#define WS_W     163840   // 512x128 f16 (C*S = Ch*L), XOR-swizzled rows
#define WS_SH    294912   // 128x128 f16 (S = L*L), XOR-swizzled rows
#define WS_CQ    327680   // 512 f32  (1024 - 0.5|chat|^2)
#define WS_CNT   329728   // 8 x 512 u32 (XCD replicas, zeroed by k_prep1)
#define WS_SUMS  346112   // 8 x 32 f32  (XCD replicas, zeroed by k_prep1)

#define MFMA16(A, B, C) __builtin_amdgcn_mfma_f32_16x16x32_f16(A, B, C, 0, 0, 0)

// byte offset of element (row, colh[halfwords]) in a 256B-row f16 matrix,
// with XOR swizzle spreading the 16 rows of a tile across banks.
__device__ __forceinline__ int moff(int row, int colh) {
  return row * 256 + ((((row & 7) << 4) ^ (colh * 2)));
}

// stage one 4KB tile (16 rows x 256B) from global to LDS, linear copy.
// 256 threads x 16B. LDS dest is wave-uniform base; HW adds lane*16.
__device__ __forceinline__ void stage4k(const char* src, char* ldsbase,
                                        int w, int lane) {
  __builtin_amdgcn_global_load_lds(
      (const __attribute__((address_space(1))) void*)(src + (w * 1024 + lane * 16)),
      (__attribute__((address_space(3))) void*)(ldsbase + w * 1024),
      16, 0, 0);
}

// ---------------- prep1: mu, trace, L rows (f16); zero counters ----------
// 64 blocks x 256. Block b: L rows 2b, 2b+1 (Gram trick, no cov materialized).
__global__ __launch_bounds__(256) void k_prep1(
    const float* __restrict__ cb, _Float16* __restrict__ Lh,
    unsigned* __restrict__ cnt, float* __restrict__ sums) {
  __shared__ float mu[128];
  __shared__ float red[256];
  __shared__ float colI[2][512];
  __shared__ float csh[2];

  const int t = threadIdx.x, b = blockIdx.x;
  const int j = t & 127, h = t >> 7;

  // zero atomic replicas for k_main
  if (b < 8) {
    cnt[b * 512 + t] = 0u;
    cnt[b * 512 + 256 + t] = 0u;
  }
  if (b == 8) sums[t] = 0.f;  // only t<256 exists; sums is 256 floats

  // column means + column sumsq (for trace)
  float sm = 0.f, sf = 0.f;
  for (int p = 0; p < 256; ++p) {
    float v = cb[(h * 256 + p) * DIM + j];
    sm += v;
    sf += v * v;
  }
  red[t] = sm;
  // stage columns 2b, 2b+1
  for (int k = t; k < 1024; k += 256)
    colI[k >> 9][k & 511] = cb[(k & 511) * DIM + 2 * b + (k >> 9)];
  __syncthreads();
  if (t < 128) mu[t] = (red[t] + red[t + 128]) * (1.f / 512.f);
  __syncthreads();
  red[t] = sf - ((t < 128) ? 512.f * mu[t] * mu[t] : 0.f);
  __syncthreads();
  for (int k = 128; k > 0; k >>= 1) {
    if (t < k) red[t] += red[t + k];
    __syncthreads();
  }
  if (t == 0) {
    float tr = red[0] * (1.f / 511.f) + 0.128f;  // + 128*1e-3 ridge
    csh[0] = 128.f / tr;
    csh[1] = sqrtf(128.f / tr);
  }
  __syncthreads();
  const float c = csh[0], rc = csh[1];

  // L row i = 2b+h:  L = rc*[ (1.5 - 5e-4c) I - (c/1022)(G - 512 mu mu^T) ]
  const int i = 2 * b + h;
  float g = 0.f;
  for (int q = 0; q < 512; ++q) g += colI[h][q] * cb[q * DIM + j];
  float lv = rc * (((i == j) ? (1.5f - 5e-4f * c) : 0.f) -
                   (c / 1022.f) * (g - 512.f * mu[i] * mu[j]));
  *(_Float16*)((char*)Lh + moff(i, j)) = (_Float16)lv;  // swizzled store
}

// ---------------- prep2: Chat = C*L (f16 MFMA, L symmetric), cqb ----------
// 32 blocks x 256. Block b: codes p0=16b..p0+15.
__global__ __launch_bounds__(256) void k_prep2(
    const float* __restrict__ cb, const _Float16* __restrict__ Lh,
    _Float16* __restrict__ Ch, float* __restrict__ cqb) {
  __shared__ float cqpart[16][4];
  const int t = threadIdx.x;
  const int w = t >> 6, lane = t & 63, quad = lane >> 4, l16 = lane & 15;
  const int p0 = blockIdx.x * 16;

  // A fragment: A[m=l16][k=quad*8+jj] = cb[p0+l16][k] (fp32 -> f16)
  half8 a[4];
#pragma unroll
  for (int ci = 0; ci < 4; ++ci) {
    const float4* v = (const float4*)(cb + (p0 + l16) * DIM + ci * 32 + quad * 8);
    float4 v0 = v[0], v1 = v[1];
    half8 hh;
    hh[0] = (_Float16)v0.x; hh[1] = (_Float16)v0.y;
    hh[2] = (_Float16)v0.z; hh[3] = (_Float16)v0.w;
    hh[4] = (_Float16)v1.x; hh[5] = (_Float16)v1.y;
    hh[6] = (_Float16)v1.z; hh[7] = (_Float16)v1.w;
    a[ci] = hh;
  }
  float sq[4] = {0.f, 0.f, 0.f, 0.f};
#pragma unroll
  for (int t2 = 0; t2 < 2; ++t2) {
    const int tile = w * 2 + t2;  // col tile: cols tile*16..+15
    floatx4 s = {0.f, 0.f, 0.f, 0.f};
#pragma unroll
    for (int ci = 0; ci < 4; ++ci) {
      // B[n][k] = L[k][n] = Lh[n][k] by symmetry -> swizzled row read
      half8 bb = *(const half8*)((const char*)Lh +
                                 moff(tile * 16 + l16, ci * 32 + quad * 8));
      s = MFMA16(a[ci], bb, s);
    }
#pragma unroll
    for (int r = 0; r < 4; ++r) {
      *(_Float16*)((char*)Ch + moff(p0 + quad * 4 + r, tile * 16 + l16)) =
          (_Float16)s[r];  // swizzled store
      sq[r] += s[r] * s[r];
    }
  }
#pragma unroll
  for (int r = 0; r < 4; ++r) {
    float v = sq[r];
    v += __shfl_xor(v, 1); v += __shfl_xor(v, 2);
    v += __shfl_xor(v, 4); v += __shfl_xor(v, 8);
    sq[r] = v;
  }
  if (l16 == 0)
#pragma unroll
    for (int r = 0; r < 4; ++r) cqpart[quad * 4 + r][w] = sq[r];
  __syncthreads();
  if (t < 16)
    cqb[p0 + t] = 1024.f - 0.5f * (cqpart[t][0] + cqpart[t][1] +
                                   cqpart[t][2] + cqpart[t][3]);
}

// ---------------- prep3: W = Ch*L (512x128), Sh = L*L (128x128) ----------
// 40 blocks x 256. Blocks 0..31: W rows 16b. Blocks 32..39: Sh rows 16(b-32).
__global__ __launch_bounds__(256) void k_prep3(
    const _Float16* __restrict__ Lh, const _Float16* __restrict__ Ch,
    _Float16* __restrict__ W, _Float16* __restrict__ Sh) {
  const int t = threadIdx.x;
  const int w = t >> 6, lane = t & 63, quad = lane >> 4, l16 = lane & 15;
  const bool isW = blockIdx.x < 32;
  const int p0 = (isW ? blockIdx.x : (blockIdx.x - 32)) * 16;
  const char* Asrc = isW ? (const char*)Ch : (const char*)Lh;
  char* Dst = isW ? (char*)W : (char*)Sh;

  half8 a[4];
#pragma unroll
  for (int ci = 0; ci < 4; ++ci)
    a[ci] = *(const half8*)(Asrc + moff(p0 + l16, ci * 32 + quad * 8));
#pragma unroll
  for (int t2 = 0; t2 < 2; ++t2) {
    const int tile = w * 2 + t2;  // col tile: cols tile*16..+15
    floatx4 s = {0.f, 0.f, 0.f, 0.f};
#pragma unroll
    for (int ci = 0; ci < 4; ++ci) {
      // B[n][k] = L[k][n] = Lh[n][k] by symmetry
      half8 bb = *(const half8*)((const char*)Lh +
                                 moff(tile * 16 + l16, ci * 32 + quad * 8));
      s = MFMA16(a[ci], bb, s);
    }
#pragma unroll
    for (int r = 0; r < 4; ++r)
      *(_Float16*)(Dst + moff(p0 + quad * 4 + r, tile * 16 + l16)) =
          (_Float16)s[r];
  }
}

// ---------------- main fused kernel ----------------
// 1024 blocks x 256 (128 rows/block; wave owns 32 rows; 4 blocks/CU).
// Single 40-tile B sweep: tiles 0..7 = Sh (xSx), 8..39 = W (packed argmax).
// A-fragments = staged X, loaded once. 2-buffer LDS staging (R2 regime).
__global__ __launch_bounds__(256, 3) void k_main(
    const float* __restrict__ X, const float* __restrict__ cb,
    const _Float16* __restrict__ Sh, const _Float16* __restrict__ W,
    const float* __restrict__ cqb, float* __restrict__ out,
    unsigned* __restrict__ cnt, float* __restrict__ sums) {
  __shared__ __align__(16) char Xs[32768];      // 128x128 f16, XOR-swizzled
  __shared__ __align__(16) char Bst[2][4096];   // B-tile double buffer

  const int tid = threadIdx.x;
  const int w = tid >> 6, lane = tid & 63;
  const int quad = lane >> 4, l16 = lane & 15;
  const int R0 = blockIdx.x * 128;
  const int rep = blockIdx.x & 7;
  const int r0 = w * 32;                         // this wave's 32 rows
  const int brot = (blockIdx.x >> 3) & 31;       // W sweep rotation (block)

  const char* ShB = (const char*)Sh;
  const char* WB = (const char*)W;

  // ---- Phase A: stage 128x128 fp32 -> f16 LDS (block-wide, swizzled) ----
  {
    const float4* src = (const float4*)(X + (size_t)R0 * DIM);
#pragma unroll
    for (int it = 0; it < 8; ++it) {
      int g = it * 256 + tid;  // 32B f32 granule id (2048 total)
      int row = g >> 4, c8 = g & 15;
      float4 v0 = src[g * 2];
      float4 v1 = src[g * 2 + 1];
      half8 hh;
      hh[0] = (_Float16)v0.x; hh[1] = (_Float16)v0.y;
      hh[2] = (_Float16)v0.z; hh[3] = (_Float16)v0.w;
      hh[4] = (_Float16)v1.x; hh[5] = (_Float16)v1.y;
      hh[6] = (_Float16)v1.z; hh[7] = (_Float16)v1.w;
      *(half8*)(Xs + moff(row, c8 * 8)) = hh;
    }
  }

  // prologue: stage tile 0 (Sh tile 0)
  stage4k(ShB, Bst[0], w, lane);
  __syncthreads();  // Xs staged + Bst[0] ready

  // A fragments (X rows of this wave) — loaded ONCE, used in all 40 iters
  half8 a0[4], a1[4];
#pragma unroll
  for (int ci = 0; ci < 4; ++ci) {
    a0[ci] = *(const half8*)(Xs + moff(r0 + l16, ci * 32 + quad * 8));
    a1[ci] = *(const half8*)(Xs + moff(r0 + 16 + l16, ci * 32 + quad * 8));
  }

  float y2 = 0.f;
  float m0[4] = {0.f, 0.f, 0.f, 0.f}, m1[4] = {0.f, 0.f, 0.f, 0.f};

  for (int v = 0; v < 40; ++v) {
    // stage tile v+1 into the other buffer
    if (v < 39) {
      const char* nsrc = (v + 1 < 8)
                             ? (ShB + (size_t)(v + 1) * 4096)
                             : (WB + (size_t)((v + 1 - 8 + brot) & 31) * 4096);
      stage4k(nsrc, Bst[(v + 1) & 1], w, lane);
    }

    const char* lb = Bst[v & 1];
    half8 bb[4];
#pragma unroll
    for (int ci = 0; ci < 4; ++ci)
      bb[ci] = *(const half8*)(lb + moff(l16, ci * 32 + quad * 8));

    if (v < 8) {
      // ---- z iter: z = X @ Sh tile, y2 += z .* x ----
      floatx4 s0a = {0.f, 0.f, 0.f, 0.f}, s0b = {0.f, 0.f, 0.f, 0.f};
      floatx4 s1a = {0.f, 0.f, 0.f, 0.f}, s1b = {0.f, 0.f, 0.f, 0.f};
      __builtin_amdgcn_s_setprio(1);
      s0a = MFMA16(a0[0], bb[0], s0a); s0b = MFMA16(a0[1], bb[1], s0b);
      s1a = MFMA16(a1[0], bb[0], s1a); s1b = MFMA16(a1[1], bb[1], s1b);
      s0a = MFMA16(a0[2], bb[2], s0a); s0b = MFMA16(a0[3], bb[3], s0b);
      s1a = MFMA16(a1[2], bb[2], s1a); s1b = MFMA16(a1[3], bb[3], s1b);
      __builtin_amdgcn_s_setprio(0);
      const int col = v * 16 + l16;
#pragma unroll
      for (int r = 0; r < 4; ++r) {
        float xv0 = (float)*(const _Float16*)(Xs + moff(r0 + quad * 4 + r, col));
        float xv1 = (float)*(const _Float16*)(Xs + moff(r0 + 16 + quad * 4 + r, col));
        y2 += (s0a[r] + s0b[r]) * xv0 + (s1a[r] + s1b[r]) * xv1;
      }
    } else {
      // ---- argmax iter over W tile tt ----
      const int tt = (v - 8 + brot) & 31;
      const float iv = cqb[tt * 16 + l16];  // 64B L1-hot line
      floatx4 s0a = {iv, iv, iv, iv}, s0b = {0.f, 0.f, 0.f, 0.f};
      floatx4 s1a = {iv, iv, iv, iv}, s1b = {0.f, 0.f, 0.f, 0.f};
      __builtin_amdgcn_s_setprio(1);
      s0a = MFMA16(a0[0], bb[0], s0a); s0b = MFMA16(a0[1], bb[1], s0b);
      s1a = MFMA16(a1[0], bb[0], s1a); s1b = MFMA16(a1[1], bb[1], s1b);
      s0a = MFMA16(a0[2], bb[2], s0a); s0b = MFMA16(a0[3], bb[3], s0b);
      s1a = MFMA16(a1[2], bb[2], s1a); s1b = MFMA16(a1[3], bb[3], s1b);
      __builtin_amdgcn_s_setprio(0);
      const unsigned tag = 511u - (unsigned)(tt * 16 + l16);
#pragma unroll
      for (int r = 0; r < 4; ++r) {
        float v0 = s0a[r] + s0b[r], v1 = s1a[r] + s1b[r];
        unsigned u0 = ((__float_as_uint(v0) + 0x100u) & 0xFFFFFE00u) | tag;
        unsigned u1 = ((__float_as_uint(v1) + 0x100u) & 0xFFFFFE00u) | tag;
        m0[r] = fmaxf(m0[r], __uint_as_float(u0));
        m1[r] = fmaxf(m1[r], __uint_as_float(u1));
      }
    }
    __syncthreads();  // stage(v+1) landed; all waves done with Bst[v&1]
  }

  // cross-lane max over the 16 lanes sharing each row (packed: ties -> low idx)
#pragma unroll
  for (int r = 0; r < 4; ++r) {
#pragma unroll
    for (int msk = 1; msk < 16; msk <<= 1) {
      m0[r] = fmaxf(m0[r], __shfl_xor(m0[r], msk));
      m1[r] = fmaxf(m1[r], __shfl_xor(m1[r], msk));
    }
  }

  // ---- epilogue (no LDS needed: every lane of quad q knows its 8 rows) ----
  float contrib = y2;
  if (l16 == 0) {
#pragma unroll
    for (int r = 0; r < 4; ++r) {
      contrib -= 2.f * (__uint_as_float(__float_as_uint(m0[r]) & 0xFFFFFE00u) - 1024.f);
      contrib -= 2.f * (__uint_as_float(__float_as_uint(m1[r]) & 0xFFFFFE00u) - 1024.f);
    }
  }
#pragma unroll
  for (int msk = 1; msk < 64; msk <<= 1) contrib += __shfl_xor(contrib, msk);
  if (lane == 0) unsafeAtomicAdd(&sums[rep * 32], contrib);

  // gather quantized rows (codebook L2-resident) + idx store + histogram
  {
    const float4* cb4 = (const float4*)cb;
    float4* out4 = (float4*)out;
#pragma unroll
    for (int r = 0; r < 4; ++r) {
      const int j0 = 511 - (int)(__float_as_uint(m0[r]) & 511u);
      const int j1 = 511 - (int)(__float_as_uint(m1[r]) & 511u);
      const int row0 = R0 + r0 + quad * 4 + r, row1 = row0 + 16;
      out4[(size_t)row0 * 32 + l16 * 2]     = cb4[(size_t)j0 * 32 + l16 * 2];
      out4[(size_t)row0 * 32 + l16 * 2 + 1] = cb4[(size_t)j0 * 32 + l16 * 2 + 1];
      out4[(size_t)row1 * 32 + l16 * 2]     = cb4[(size_t)j1 * 32 + l16 * 2];
      out4[(size_t)row1 * 32 + l16 * 2 + 1] = cb4[(size_t)j1 * 32 + l16 * 2 + 1];
      if (l16 == 0) {
        out[ND + 2 + row0] = (float)j0;
        out[ND + 2 + row1] = (float)j1;
        atomicAdd(&cnt[rep * 512 + j0], 1u);
        atomicAdd(&cnt[rep * 512 + j1], 1u);
      }
    }
  }
}

// ---------------- finalize: entropy + losses ----------------
__global__ void k_final(const unsigned* __restrict__ cnt,
                        const float* __restrict__ sums, float* __restrict__ out) {
  __shared__ double sd[256];
  int t = threadIdx.x;
  double e = 0.0;
  for (int c = t; c < NCODE; c += 256) {
    unsigned u = 0;
#pragma unroll
    for (int r = 0; r < 8; ++r) u += cnt[r * 512 + c];
    float p = (float)u * (1.0f / 131072.0f);
    e += (double)(p * logf(p + 1e-8f));
  }
  sd[t] = e;
  __syncthreads();
  for (int k = 128; k > 0; k >>= 1) {
    if (t < k) sd[t] += sd[t + k];
    __syncthreads();
  }
  if (t == 0) {
    double ent = -sd[0];
    float st = 0.f;
#pragma unroll
    for (int r = 0; r < 8; ++r) st += sums[r * 32];
    double M = (double)st / 131072.0;
    out[ND] = (float)(0.1 * M);
    out[ND + 1] = (float)(M - 200000.0 * ent);
  }
}

// ---------------- launcher ----------------
extern "C" void kernel_launch(void* const* d_in, const int* in_sizes, int n_in,
                              void* d_out, int out_size, void* d_ws, size_t ws_size,
                              hipStream_t stream) {
  const float* X = (const float*)d_in[0];
  const float* cb = (const float*)d_in[1];
  char* ws = (char*)d_ws;
  _Float16* Lh = (_Float16*)(ws + WS_LH);
  _Float16* Ch = (_Float16*)(ws + WS_CH);
  _Float16* W = (_Float16*)(ws + WS_W);
  _Float16* Sh = (_Float16*)(ws + WS_SH);
  float* cqb = (float*)(ws + WS_CQ);
  unsigned* cnt = (unsigned*)(ws + WS_CNT);
  float* sums = (float*)(ws + WS_SUMS);
  float* out = (float*)d_out;

  k_prep1<<<64, 256, 0, stream>>>(cb, Lh, cnt, sums);
  k_prep2<<<32, 256, 0, stream>>>(cb, Lh, Ch, cqb);
  k_prep3<<<40, 256, 0, stream>>>(Lh, Ch, W, Sh);
  k_main<<<1024, 256, 0, stream>>>(X, cb, Sh, W, cqb, out, cnt, sums);
  k_final<<<1, 256, 0, stream>>>(cnt, sums, out);
}